// Round 3
// baseline (865.507 us; speedup 1.0000x reference)
//
#include <hip/hip_runtime.h>

#define TSEQ 2048
#define CDIM 1024
#define NH 16
#define HS 64

// ---------------- GEMM: Out = epilogue(X @ W) ----------------
// X: MxK row-major, W: KxN row-major, Out: MxN row-major.
// MODE 0: relu(acc + bN[c] + bH[c & 63])   (H = relu(x@W1 + bw1 + b1))
// MODE 1: acc + bN[c]                      (V / final projection)
template<int MODE>
__global__ __launch_bounds__(256, 2)
void gemm128(const float* __restrict__ X, const float* __restrict__ W,
             const float* __restrict__ bN, const float* __restrict__ bH,
             float* __restrict__ Out, int M, int N, int K)
{
    __shared__ float Xs[16][128];   // [k][m]  (transposed for stride-1 m reads)
    __shared__ float Ws[16][128];   // [k][n]
    const int tid = threadIdx.x;
    const int ty = tid >> 4, tx = tid & 15;
    const int m0 = blockIdx.y * 128, n0 = blockIdx.x * 128;

    float acc[8][8];
    #pragma unroll
    for (int i = 0; i < 8; i++)
        #pragma unroll
        for (int j = 0; j < 8; j++) acc[i][j] = 0.f;

    const int xr = tid >> 2;            // 0..63 (rows xr, xr+64)
    const int xk = (tid & 3) * 4;       // 0,4,8,12
    const int wk = tid >> 5;            // 0..7  (k rows wk, wk+8)
    const int wc = (tid & 31) * 4;      // 0..124

    for (int k0 = 0; k0 < K; k0 += 16) {
        float4 xa = *(const float4*)(X + (size_t)(m0 + xr)      * K + k0 + xk);
        float4 xb = *(const float4*)(X + (size_t)(m0 + xr + 64) * K + k0 + xk);
        float4 wa = *(const float4*)(W + (size_t)(k0 + wk)     * N + n0 + wc);
        float4 wb = *(const float4*)(W + (size_t)(k0 + wk + 8) * N + n0 + wc);
        __syncthreads();   // previous iteration's LDS reads complete
        Xs[xk+0][xr]    = xa.x; Xs[xk+1][xr]    = xa.y; Xs[xk+2][xr]    = xa.z; Xs[xk+3][xr]    = xa.w;
        Xs[xk+0][xr+64] = xb.x; Xs[xk+1][xr+64] = xb.y; Xs[xk+2][xr+64] = xb.z; Xs[xk+3][xr+64] = xb.w;
        *(float4*)&Ws[wk][wc]     = wa;
        *(float4*)&Ws[wk + 8][wc] = wb;
        __syncthreads();
        #pragma unroll
        for (int k = 0; k < 16; k++) {
            float a[8], b[8];
            *(float4*)(a)     = *(const float4*)&Xs[k][ty*8];
            *(float4*)(a + 4) = *(const float4*)&Xs[k][ty*8 + 4];
            *(float4*)(b)     = *(const float4*)&Ws[k][tx*8];
            *(float4*)(b + 4) = *(const float4*)&Ws[k][tx*8 + 4];
            #pragma unroll
            for (int i = 0; i < 8; i++)
                #pragma unroll
                for (int j = 0; j < 8; j++)
                    acc[i][j] = fmaf(a[i], b[j], acc[i][j]);
        }
    }

    #pragma unroll
    for (int i = 0; i < 8; i++) {
        const int r = m0 + ty*8 + i;
        float o[8];
        #pragma unroll
        for (int j = 0; j < 8; j++) {
            const int c = n0 + tx*8 + j;
            float v = acc[i][j];
            if (MODE == 0) v = fmaxf(v + bN[c] + bH[c & (HS - 1)], 0.f);
            else           v = v + bN[c];
            o[j] = v;
        }
        *(float4*)(Out + (size_t)r * N + n0 + tx*8)     = *(float4*)(o);
        *(float4*)(Out + (size_t)r * N + n0 + tx*8 + 4) = *(float4*)(o + 4);
    }
}

// ---------------- Fused synthesizer attention ----------------
// Per block: one (batch b, head h, 64-row q-tile). Iterates causal k-tiles of 64.
// Scores s = H_tile(64x64) @ w2_tile(64x64) + b2; |s| <= ~0.4 so exp() needs no
// max subtraction. Single-pass: l += sum(P), y += P @ V_tile; divide at end.
__global__ __launch_bounds__(256, 2)
void synth_attn(const float* __restrict__ H, const float* __restrict__ V,
                const float* __restrict__ w2, const float* __restrict__ b2,
                float* __restrict__ Y)
{
    __shared__ float Hs[HS][64];     // [d][r]
    __shared__ float Ks[HS][64];     // w2 tile [d][c]
    __shared__ float Vs[64][HS];     // [c][d]
    __shared__ float Ps[64][64];     // [r][c]
    __shared__ float Lr[16][4][16];  // [ty][i][tx] partial row sums

    const int tid = threadIdx.x;
    const int ty = tid >> 4, tx = tid & 15;
    const int q0 = blockIdx.x * 64;
    const int h  = blockIdx.y;
    const int b  = blockIdx.z;

    const float* Hb = H + ((size_t)b * TSEQ) * CDIM + h * HS;
    const float* Vb = V + ((size_t)b * TSEQ) * CDIM + h * HS;

    // Load q-tile of H, transposed into [d][r] (once per block).
    {
        const int rr = tid >> 4;
        const int d0 = (tid & 15) * 4;
        #pragma unroll
        for (int u = 0; u < 4; u++) {
            const int r = rr + u * 16;
            float4 xv = *(const float4*)(Hb + (size_t)(q0 + r) * CDIM + d0);
            Hs[d0+0][r] = xv.x; Hs[d0+1][r] = xv.y; Hs[d0+2][r] = xv.z; Hs[d0+3][r] = xv.w;
        }
    }

    float yacc[4][4];
    #pragma unroll
    for (int i = 0; i < 4; i++)
        #pragma unroll
        for (int j = 0; j < 4; j++) yacc[i][j] = 0.f;
    float lacc[4] = {0.f, 0.f, 0.f, 0.f};

    const int ntile = (q0 >> 6) + 1;
    for (int kt = 0; kt < ntile; kt++) {
        const int k0 = kt << 6;
        __syncthreads();   // Hs ready (iter 0); prev PV done with Ps/Vs (later)
        {
            const int a  = tid >> 4;
            const int c0 = (tid & 15) * 4;
            #pragma unroll
            for (int u = 0; u < 4; u++) {
                const int d = a + u * 16;
                *(float4*)&Ks[d][c0] = *(const float4*)(w2 + (size_t)d * TSEQ + k0 + c0);
            }
            #pragma unroll
            for (int u = 0; u < 4; u++) {
                const int c = a + u * 16;
                *(float4*)&Vs[c][c0] = *(const float4*)(Vb + (size_t)(k0 + c) * CDIM + c0);
            }
        }
        __syncthreads();

        // scores: s[i][j] over rows r=ty*4+i, cols c=tx*4+j
        float s[4][4];
        #pragma unroll
        for (int i = 0; i < 4; i++)
            #pragma unroll
            for (int j = 0; j < 4; j++) s[i][j] = 0.f;
        #pragma unroll 8
        for (int d = 0; d < HS; d++) {
            float a4[4], b4[4];
            *(float4*)a4 = *(const float4*)&Hs[d][ty*4];
            *(float4*)b4 = *(const float4*)&Ks[d][tx*4];
            #pragma unroll
            for (int i = 0; i < 4; i++)
                #pragma unroll
                for (int j = 0; j < 4; j++)
                    s[i][j] = fmaf(a4[i], b4[j], s[i][j]);
        }

        const bool diag = (k0 == q0);
        float bb[4];
        *(float4*)bb = *(const float4*)(b2 + k0 + tx*4);
        #pragma unroll
        for (int i = 0; i < 4; i++) {
            float p[4];
            #pragma unroll
            for (int j = 0; j < 4; j++) {
                float e = __expf(s[i][j] + bb[j]);
                if (diag && (tx*4 + j > ty*4 + i)) e = 0.f;   // causal mask
                p[j] = e;
                lacc[i] += e;
            }
            *(float4*)&Ps[ty*4 + i][tx*4] = *(float4*)p;
        }
        __syncthreads();

        // y += P @ V_tile
        #pragma unroll 4
        for (int c4 = 0; c4 < 64; c4 += 4) {
            float pa[4][4];
            #pragma unroll
            for (int i = 0; i < 4; i++)
                *(float4*)pa[i] = *(const float4*)&Ps[ty*4 + i][c4];
            #pragma unroll
            for (int cc = 0; cc < 4; cc++) {
                float vb4[4];
                *(float4*)vb4 = *(const float4*)&Vs[c4 + cc][tx*4];
                #pragma unroll
                for (int i = 0; i < 4; i++)
                    #pragma unroll
                    for (int j = 0; j < 4; j++)
                        yacc[i][j] = fmaf(pa[i][cc], vb4[j], yacc[i][j]);
            }
        }
    }

    // reduce row sums across tx, normalize, write Y
    #pragma unroll
    for (int i = 0; i < 4; i++) Lr[ty][i][tx] = lacc[i];
    __syncthreads();
    float* Yb = Y + ((size_t)b * TSEQ) * CDIM + h * HS;
    #pragma unroll
    for (int i = 0; i < 4; i++) {
        float l = 0.f;
        #pragma unroll
        for (int t = 0; t < 16; t++) l += Lr[ty][i][t];
        const float inv = 1.0f / l;
        float o[4];
        #pragma unroll
        for (int j = 0; j < 4; j++) o[j] = yacc[i][j] * inv;
        *(float4*)(Yb + (size_t)(q0 + ty*4 + i) * CDIM + tx*4) = *(float4*)o;
    }
}

extern "C" void kernel_launch(void* const* d_in, const int* in_sizes, int n_in,
                              void* d_out, int out_size, void* d_ws, size_t ws_size,
                              hipStream_t stream) {
    const float* x   = (const float*)d_in[0];
    const float* W1  = (const float*)d_in[1];
    const float* bw1 = (const float*)d_in[2];
    const float* b1  = (const float*)d_in[3];
    const float* w2  = (const float*)d_in[4];
    const float* b2  = (const float*)d_in[5];
    const float* Wv  = (const float*)d_in[6];
    const float* bv  = (const float*)d_in[7];
    const float* Wp  = (const float*)d_in[8];
    const float* bp  = (const float*)d_in[9];
    float* out = (float*)d_out;

    const int B = in_sizes[0] / (TSEQ * CDIM);   // 2
    const int M = B * TSEQ;                      // 4096

    float* Hbuf = (float*)d_ws;
    float* Vbuf = Hbuf + (size_t)M * CDIM;
    float* Ybuf = Vbuf + (size_t)M * CDIM;

    dim3 blk(256);
    dim3 gg(CDIM / 128, M / 128);
    gemm128<0><<<gg, blk, 0, stream>>>(x, W1, bw1, b1, Hbuf, M, CDIM, CDIM);
    gemm128<1><<<gg, blk, 0, stream>>>(x, Wv, bv, nullptr, Vbuf, M, CDIM, CDIM);

    dim3 ga(TSEQ / 64, NH, B);
    synth_attn<<<ga, blk, 0, stream>>>(Hbuf, Vbuf, w2, b2, Ybuf);

    gemm128<1><<<gg, blk, 0, stream>>>(Ybuf, Wp, bp, nullptr, out, M, CDIM, CDIM);
}

// Round 4
// 173.707 us; speedup vs baseline: 4.9826x; 4.9826x over previous
//
#include <hip/hip_runtime.h>
#include <hip/hip_bf16.h>

#define TSEQ 2048
#define CDIM 1024
#define NH 16
#define HS 64

typedef __attribute__((ext_vector_type(8))) short bf16x8;
typedef __attribute__((ext_vector_type(4))) float f32x4;

__device__ inline void store_out(float* p, float v) { *p = v; }
__device__ inline void store_out(__hip_bfloat16* p, float v) { *p = __float2bfloat16(v); }

// ---------- elementwise f32 -> bf16 ----------
__global__ __launch_bounds__(256)
void conv_bf16(const float* __restrict__ in, __hip_bfloat16* __restrict__ out, int n) {
    int i = (blockIdx.x * 256 + threadIdx.x) * 4;
    if (i + 3 < n) {
        float4 v = *(const float4*)(in + i);
        union { ushort4 u; __hip_bfloat16 h[4]; } o;
        o.h[0] = __float2bfloat16(v.x);
        o.h[1] = __float2bfloat16(v.y);
        o.h[2] = __float2bfloat16(v.z);
        o.h[3] = __float2bfloat16(v.w);
        *(ushort4*)((unsigned short*)out + i) = o.u;
    }
}

// ---------- tiled transpose (+convert) : in [R][C] -> out [C][R] bf16 ----------
template<typename TIN>
__global__ __launch_bounds__(256)
void transpose_to_bf16(const TIN* __restrict__ in, __hip_bfloat16* __restrict__ out,
                       int R, int C) {
    __shared__ float t[32][33];
    const int tx = threadIdx.x & 31, ty = threadIdx.x >> 5;  // 32 x 8
    const int r0 = blockIdx.y * 32, c0 = blockIdx.x * 32;
    #pragma unroll
    for (int i = 0; i < 32; i += 8)
        t[ty + i][tx] = (float)in[(size_t)(r0 + ty + i) * C + c0 + tx];
    __syncthreads();
    #pragma unroll
    for (int i = 0; i < 32; i += 8)
        out[(size_t)(c0 + ty + i) * R + r0 + tx] = __float2bfloat16(t[tx][ty + i]);
}

// ---------- MFMA GEMM: Out = epi(X @ Wt^T) ----------
// X: [M][K] bf16 row-major. Wt: [N][K] bf16 row-major (pre-transposed weight).
// MODE 0: relu(acc + bN[c] + bH[c&63]) -> bf16
// MODE 1: acc + bN[c]                  -> bf16
// MODE 2: acc + bN[c]                  -> f32
template<int MODE, typename TOUT>
__global__ __launch_bounds__(256)
void gemm_mfma(const __hip_bfloat16* __restrict__ X, const __hip_bfloat16* __restrict__ Wt,
               const float* __restrict__ bN, const float* __restrict__ bH,
               TOUT* __restrict__ Out, int M, int N, int K)
{
    __shared__ __hip_bfloat16 As[128][40];   // [m][k] pad 32->40 (80B rows, 16B aligned)
    __shared__ __hip_bfloat16 Bs[128][40];   // [n][k]
    const int tid = threadIdx.x;
    const int wave = tid >> 6, lane = tid & 63;
    const int wr = wave >> 1, wc = wave & 1;
    const int l15 = lane & 15, l4 = lane >> 4;
    const int m0 = blockIdx.y * 128, n0 = blockIdx.x * 128;

    f32x4 acc[4][4] = {};

    // staging: 16B unit u -> row u>>2, k-offset (u&3)*8 bf16 (BK=32 -> 4 units/row)
    const int r0s = tid >> 2, r1s = (tid + 256) >> 2;
    const int k0s = (tid & 3) * 8;
    const size_t xrow0 = (size_t)(m0 + r0s) * K, xrow1 = (size_t)(m0 + r1s) * K;
    const size_t wrow0 = (size_t)(n0 + r0s) * K, wrow1 = (size_t)(n0 + r1s) * K;

    float4 xa = *(const float4*)(X + xrow0 + k0s);
    float4 xb = *(const float4*)(X + xrow1 + k0s);
    float4 wa = *(const float4*)(Wt + wrow0 + k0s);
    float4 wb = *(const float4*)(Wt + wrow1 + k0s);

    for (int k0 = 0; k0 < K; k0 += 32) {
        __syncthreads();
        *(float4*)&As[r0s][k0s] = xa;
        *(float4*)&As[r1s][k0s] = xb;
        *(float4*)&Bs[r0s][k0s] = wa;
        *(float4*)&Bs[r1s][k0s] = wb;
        __syncthreads();
        if (k0 + 32 < K) {
            xa = *(const float4*)(X + xrow0 + k0 + 32 + k0s);
            xb = *(const float4*)(X + xrow1 + k0 + 32 + k0s);
            wa = *(const float4*)(Wt + wrow0 + k0 + 32 + k0s);
            wb = *(const float4*)(Wt + wrow1 + k0 + 32 + k0s);
        }
        bf16x8 af[4], bfr[4];
        #pragma unroll
        for (int f = 0; f < 4; f++)
            af[f] = *(const bf16x8*)&As[wr * 64 + f * 16 + l15][l4 * 8];
        #pragma unroll
        for (int f = 0; f < 4; f++)
            bfr[f] = *(const bf16x8*)&Bs[wc * 64 + f * 16 + l15][l4 * 8];
        #pragma unroll
        for (int fr = 0; fr < 4; fr++)
            #pragma unroll
            for (int fc = 0; fc < 4; fc++)
                acc[fr][fc] = __builtin_amdgcn_mfma_f32_16x16x32_bf16(
                    af[fr], bfr[fc], acc[fr][fc], 0, 0, 0);
    }

    #pragma unroll
    for (int fr = 0; fr < 4; fr++) {
        #pragma unroll
        for (int fc = 0; fc < 4; fc++) {
            const int col = n0 + wc * 64 + fc * 16 + l15;
            float bias = bN[col];
            if (MODE == 0) bias += bH[col & (HS - 1)];
            #pragma unroll
            for (int r = 0; r < 4; r++) {
                const int row = m0 + wr * 64 + fr * 16 + l4 * 4 + r;
                float v = acc[fr][fc][r] + bias;
                if (MODE == 0) v = fmaxf(v, 0.f);
                store_out(Out + (size_t)row * N + col, v);
            }
        }
    }
}

// ---------- fused synthesizer attention (MFMA) ----------
// H: [B*T][C] bf16 (relu'd scores input), w2t: [T][HS] bf16, Vt: [C][B*T] bf16.
// Block: (q-tile of 64, head, batch). 4 waves; wave w owns q rows w*16..w*16+15.
__global__ __launch_bounds__(256)
void attn_mfma(const __hip_bfloat16* __restrict__ H, const __hip_bfloat16* __restrict__ w2t,
               const __hip_bfloat16* __restrict__ Vt, const float* __restrict__ b2,
               __hip_bfloat16* __restrict__ Y)
{
    __shared__ __hip_bfloat16 Hs[64][72];  // [q][hs]
    __shared__ __hip_bfloat16 Ks[64][72];  // [t][hs]   (w2t tile)
    __shared__ __hip_bfloat16 Vs[64][72];  // [d][t]    (Vt tile)
    __shared__ __hip_bfloat16 Ps[64][72];  // [q][t]

    const int tid = threadIdx.x;
    const int wave = tid >> 6, lane = tid & 63;
    const int l15 = lane & 15, l4 = lane >> 4;
    const int q0 = blockIdx.x * 64;
    const int h = blockIdx.y, b = blockIdx.z;

    // stage H q-tile: 64 rows x 64 cols; unit u: row u>>3, col (u&7)*8
    #pragma unroll
    for (int uu = 0; uu < 2; uu++) {
        const int u = tid + uu * 256;
        const int r = u >> 3, c8 = (u & 7) * 8;
        *(float4*)&Hs[r][c8] =
            *(const float4*)(H + (size_t)(b * TSEQ + q0 + r) * CDIM + h * HS + c8);
    }

    f32x4 yacc[4] = {};
    float lsum[4] = {0.f, 0.f, 0.f, 0.f};

    const int ntile = (q0 >> 6) + 1;
    for (int kt = 0; kt < ntile; kt++) {
        const int k0 = kt * 64;
        __syncthreads();   // prev iter's reads done; (iter 0: Hs staged)
        #pragma unroll
        for (int uu = 0; uu < 2; uu++) {
            const int u = tid + uu * 256;
            const int r = u >> 3, c8 = (u & 7) * 8;
            *(float4*)&Ks[r][c8] = *(const float4*)(w2t + (size_t)(k0 + r) * HS + c8);
            *(float4*)&Vs[r][c8] =
                *(const float4*)(Vt + (size_t)(h * HS + r) * (2 * TSEQ) + b * TSEQ + k0 + c8);
        }
        __syncthreads();

        // S = H_tile @ w2_tile : wave rows wave*16..+15, cols 0..63
        bf16x8 af[2];
        #pragma unroll
        for (int ks = 0; ks < 2; ks++)
            af[ks] = *(const bf16x8*)&Hs[wave * 16 + l15][ks * 32 + l4 * 8];
        f32x4 s[4] = {};
        #pragma unroll
        for (int tf = 0; tf < 4; tf++)
            #pragma unroll
            for (int ks = 0; ks < 2; ks++) {
                bf16x8 bk = *(const bf16x8*)&Ks[tf * 16 + l15][ks * 32 + l4 * 8];
                s[tf] = __builtin_amdgcn_mfma_f32_16x16x32_bf16(af[ks], bk, s[tf], 0, 0, 0);
            }

        // exp (no max-subtract: |s|<=~0.4), causal mask, P -> LDS bf16 (wave-local rows)
        #pragma unroll
        for (int tf = 0; tf < 4; tf++) {
            const int cg = k0 + tf * 16 + l15;
            const float b2v = b2[cg];
            #pragma unroll
            for (int r = 0; r < 4; r++) {
                const int rg = q0 + wave * 16 + l4 * 4 + r;
                float e = (cg <= rg) ? __expf(s[tf][r] + b2v) : 0.f;
                lsum[r] += e;
                Ps[wave * 16 + l4 * 4 + r][tf * 16 + l15] = __float2bfloat16(e);
            }
        }
        // no barrier: each wave consumes only its own 16 P rows

        // Y += P @ V_tile
        #pragma unroll
        for (int ks = 0; ks < 2; ks++) {
            bf16x8 pa = *(const bf16x8*)&Ps[wave * 16 + l15][ks * 32 + l4 * 8];
            #pragma unroll
            for (int df = 0; df < 4; df++) {
                bf16x8 vb = *(const bf16x8*)&Vs[df * 16 + l15][ks * 32 + l4 * 8];
                yacc[df] = __builtin_amdgcn_mfma_f32_16x16x32_bf16(pa, vb, yacc[df], 0, 0, 0);
            }
        }
    }

    // row sums: reduce across the 16 lanes sharing each row group
    #pragma unroll
    for (int r = 0; r < 4; r++) {
        float v = lsum[r];
        v += __shfl_xor(v, 1);
        v += __shfl_xor(v, 2);
        v += __shfl_xor(v, 4);
        v += __shfl_xor(v, 8);
        lsum[r] = v;
    }

    #pragma unroll
    for (int r = 0; r < 4; r++) {
        const float inv = 1.0f / lsum[r];
        const size_t row = (size_t)(b * TSEQ + q0 + wave * 16 + l4 * 4 + r);
        #pragma unroll
        for (int df = 0; df < 4; df++) {
            const int col = h * HS + df * 16 + l15;
            Y[row * CDIM + col] = __float2bfloat16(yacc[df][r] * inv);
        }
    }
}

extern "C" void kernel_launch(void* const* d_in, const int* in_sizes, int n_in,
                              void* d_out, int out_size, void* d_ws, size_t ws_size,
                              hipStream_t stream) {
    const float* x   = (const float*)d_in[0];
    const float* W1  = (const float*)d_in[1];
    const float* bw1 = (const float*)d_in[2];
    const float* b1  = (const float*)d_in[3];
    const float* w2  = (const float*)d_in[4];
    const float* b2  = (const float*)d_in[5];
    const float* Wv  = (const float*)d_in[6];
    const float* bv  = (const float*)d_in[7];
    const float* Wp  = (const float*)d_in[8];
    const float* bp  = (const float*)d_in[9];
    float* out = (float*)d_out;

    const int B = in_sizes[0] / (TSEQ * CDIM);   // 2
    const int M = B * TSEQ;                      // 4096
    const size_t MC = (size_t)M * CDIM;          // 4M
    const size_t WC = (size_t)CDIM * CDIM;       // 1M

    __hip_bfloat16* xb  = (__hip_bfloat16*)d_ws;
    __hip_bfloat16* W1t = xb  + MC;
    __hip_bfloat16* Wvt = W1t + WC;
    __hip_bfloat16* Wpt = Wvt + WC;
    __hip_bfloat16* w2t = Wpt + WC;              // [T][HS]
    __hip_bfloat16* Hb  = w2t + (size_t)TSEQ * HS;
    __hip_bfloat16* Vb  = Hb  + MC;
    __hip_bfloat16* Vtb = Vb  + MC;              // [C][M]
    __hip_bfloat16* Yb  = Vtb + MC;

    dim3 blk(256);
    conv_bf16<<<dim3((unsigned)(MC / 1024)), blk, 0, stream>>>(x, xb, (int)MC);
    transpose_to_bf16<float><<<dim3(32, 32), blk, 0, stream>>>(W1, W1t, CDIM, CDIM);
    transpose_to_bf16<float><<<dim3(32, 32), blk, 0, stream>>>(Wv, Wvt, CDIM, CDIM);
    transpose_to_bf16<float><<<dim3(32, 32), blk, 0, stream>>>(Wp, Wpt, CDIM, CDIM);
    transpose_to_bf16<float><<<dim3(TSEQ / 32, HS / 32), blk, 0, stream>>>(w2, w2t, HS, TSEQ);

    dim3 gg(CDIM / 128, M / 128);
    gemm_mfma<0, __hip_bfloat16><<<gg, blk, 0, stream>>>(xb, W1t, bw1, b1, Hb, M, CDIM, CDIM);
    gemm_mfma<1, __hip_bfloat16><<<gg, blk, 0, stream>>>(xb, Wvt, bv, nullptr, Vb, M, CDIM, CDIM);

    transpose_to_bf16<__hip_bfloat16><<<dim3(CDIM / 32, M / 32), blk, 0, stream>>>(Vb, Vtb, M, CDIM);

    attn_mfma<<<dim3(TSEQ / 64, NH, B), blk, 0, stream>>>(Hb, w2t, Vtb, b2, Yb);

    gemm_mfma<2, float><<<gg, blk, 0, stream>>>(Yb, Wpt, bp, nullptr, out, M, CDIM, CDIM);
}